// Round 1
// baseline (3146.474 us; speedup 1.0000x reference)
//
#include <hip/hip_runtime.h>
#include <cstdint>
#include <cstddef>

#define N_NODES 20000
#define T_STEPS 8
#define N_EDGES 320000
#define NFEAT 512
#define HC 512      // H*C
#define NH 4
#define CC 128
#define NHID 128
#define SLOPE 0.2f

__device__ __forceinline__ float leakyf(float x) { return x >= 0.f ? x : SLOPE * x; }

// ---------------------------------------------------------------------------
// GEMM: h = A[M,512] @ B[512,512], fp32, 128x128 tile, 8x8 microtile
// ---------------------------------------------------------------------------
#define BM 128
#define BN 128
#define BK 16

__global__ __launch_bounds__(256) void gemm_h(const float* __restrict__ A,
                                              const float* __restrict__ B,
                                              float* __restrict__ C) {
  __shared__ float As[BK][BM];   // transposed A tile
  __shared__ float Bs[BK][BN];
  const int tid = threadIdx.x;
  const int tx = tid & 15;
  const int ty = tid >> 4;
  const int bx = blockIdx.x;     // over N=512 (4 tiles)
  const int by = blockIdx.y;     // over M=20000 (157 tiles)
  const int row0 = by * BM;

  float acc[8][8];
#pragma unroll
  for (int i = 0; i < 8; ++i)
#pragma unroll
    for (int j = 0; j < 8; ++j) acc[i][j] = 0.f;

  const int a_r = tid >> 1;
  const int a_c = (tid & 1) * 8;
  const int b_r = tid >> 4;
  const int b_c = (tid & 15) * 8;

  for (int k0 = 0; k0 < NFEAT; k0 += BK) {
    int ar = row0 + a_r; ar = ar < N_NODES ? ar : N_NODES - 1;
    const float4 av0 = *(const float4*)(A + (size_t)ar * NFEAT + k0 + a_c);
    const float4 av1 = *(const float4*)(A + (size_t)ar * NFEAT + k0 + a_c + 4);
    As[a_c + 0][a_r] = av0.x; As[a_c + 1][a_r] = av0.y;
    As[a_c + 2][a_r] = av0.z; As[a_c + 3][a_r] = av0.w;
    As[a_c + 4][a_r] = av1.x; As[a_c + 5][a_r] = av1.y;
    As[a_c + 6][a_r] = av1.z; As[a_c + 7][a_r] = av1.w;
    const float4 bv0 = *(const float4*)(B + (size_t)(k0 + b_r) * HC + bx * BN + b_c);
    const float4 bv1 = *(const float4*)(B + (size_t)(k0 + b_r) * HC + bx * BN + b_c + 4);
    *(float4*)&Bs[b_r][b_c] = bv0;
    *(float4*)&Bs[b_r][b_c + 4] = bv1;
    __syncthreads();
#pragma unroll
    for (int kk = 0; kk < BK; ++kk) {
      float a[8], b[8];
#pragma unroll
      for (int i = 0; i < 8; ++i) a[i] = As[kk][ty * 8 + i];
#pragma unroll
      for (int j = 0; j < 8; ++j) b[j] = Bs[kk][tx * 8 + j];
#pragma unroll
      for (int i = 0; i < 8; ++i)
#pragma unroll
        for (int j = 0; j < 8; ++j) acc[i][j] = fmaf(a[i], b[j], acc[i][j]);
    }
    __syncthreads();
  }
#pragma unroll
  for (int i = 0; i < 8; ++i) {
    int r = row0 + ty * 8 + i;
    if (r < N_NODES) {
      float* cp = C + (size_t)r * HC + bx * BN + tx * 8;
      float4 v0 = {acc[i][0], acc[i][1], acc[i][2], acc[i][3]};
      float4 v1 = {acc[i][4], acc[i][5], acc[i][6], acc[i][7]};
      *(float4*)cp = v0;
      *(float4*)(cp + 4) = v1;
    }
  }
}

// ---------------------------------------------------------------------------
// per-(node,head) attention logits
// ---------------------------------------------------------------------------
__global__ void att_kernel(const float* __restrict__ hbuf,
                           const float* __restrict__ att_src,
                           const float* __restrict__ att_dst,
                           float* __restrict__ a_src, float* __restrict__ a_dst) {
  int idx = blockIdx.x * blockDim.x + threadIdx.x;
  if (idx >= N_NODES * NH) return;
  int n = idx >> 2, hh = idx & 3;
  const float* hp = hbuf + (size_t)n * HC + hh * CC;
  const float* ps = att_src + hh * CC;
  const float* pd = att_dst + hh * CC;
  float s = 0.f, d = 0.f;
#pragma unroll 4
  for (int c = 0; c < CC; c += 4) {
    float4 hv = *(const float4*)(hp + c);
    float4 sv = *(const float4*)(ps + c);
    float4 dv = *(const float4*)(pd + c);
    s += hv.x * sv.x + hv.y * sv.y + hv.z * sv.z + hv.w * sv.w;
    d += hv.x * dv.x + hv.y * dv.y + hv.z * dv.z + hv.w * dv.w;
  }
  a_src[idx] = s;
  a_dst[idx] = d;
}

// ---------------------------------------------------------------------------
// CSR build (all T at once)
// ---------------------------------------------------------------------------
__global__ void count_kernel(const int* __restrict__ graph, int* __restrict__ deg) {
  int idx = blockIdx.x * blockDim.x + threadIdx.x;
  if (idx >= T_STEPS * N_EDGES) return;
  int t = idx / N_EDGES, e = idx - t * N_EDGES;
  int d = graph[(size_t)t * 2 * N_EDGES + N_EDGES + e];
  atomicAdd(&deg[t * N_NODES + d], 1);
}

__global__ __launch_bounds__(1024) void scan_kernel(const int* __restrict__ deg,
                                                    int* __restrict__ rowptr) {
  int t = blockIdx.x;
  const int* dp = deg + t * N_NODES;
  int* rp = rowptr + t * (N_NODES + 1);
  __shared__ int s_sums[16];
  __shared__ int s_carry;
  int lane = threadIdx.x & 63;
  int wid = threadIdx.x >> 6;
  if (threadIdx.x == 0) { s_carry = 0; rp[0] = 0; }
  __syncthreads();
  for (int base = 0; base < N_NODES; base += 1024) {
    int i = base + threadIdx.x;
    int v = (i < N_NODES) ? dp[i] : 0;
    int x = v;
#pragma unroll
    for (int off = 1; off < 64; off <<= 1) {
      int y = __shfl_up(x, off);
      if (lane >= off) x += y;
    }
    if (lane == 63) s_sums[wid] = x;
    __syncthreads();
    if (threadIdx.x < 16) {
      int ws = s_sums[threadIdx.x];
#pragma unroll
      for (int off = 1; off < 16; off <<= 1) {
        int y = __shfl_up(ws, off);
        if (threadIdx.x >= off) ws += y;
      }
      s_sums[threadIdx.x] = ws;
    }
    __syncthreads();
    int add = s_carry + (wid > 0 ? s_sums[wid - 1] : 0);
    if (i < N_NODES) rp[i + 1] = x + add;
    __syncthreads();
    if (threadIdx.x == 0) s_carry += s_sums[15];
    __syncthreads();
  }
}

__global__ void scatter_kernel(const int* __restrict__ graph, const int* __restrict__ rowptr,
                               int* __restrict__ fill, int* __restrict__ ssrc) {
  int idx = blockIdx.x * blockDim.x + threadIdx.x;
  if (idx >= T_STEPS * N_EDGES) return;
  int t = idx / N_EDGES, e = idx - t * N_EDGES;
  const int* g = graph + (size_t)t * 2 * N_EDGES;
  int s = g[e], d = g[N_EDGES + e];
  int pos = rowptr[t * (N_NODES + 1) + d] + atomicAdd(&fill[t * N_NODES + d], 1);
  ssrc[(size_t)t * N_EDGES + pos] = s;
}

// ---------------------------------------------------------------------------
// GAT aggregation: one block per dst node, 512 threads (one per h*c element)
// softmax without max-subtraction (logits are tiny); mean over heads + bias + leaky
// ---------------------------------------------------------------------------
__global__ __launch_bounds__(512) void aggregate_kernel(const float* __restrict__ hbuf,
    const float* __restrict__ a_src, const float* __restrict__ a_dst,
    const int* __restrict__ rowptr, const int* __restrict__ ssrc,
    const float* __restrict__ b_gat, float* __restrict__ y) {
  const int n = blockIdx.x;
  const int tid = threadIdx.x;
  const int hh = tid >> 7;
  __shared__ int s_idx[64];
  __shared__ float s_w[64 * 4];
  __shared__ float s_res[512];

  float4 ad = *(const float4*)(a_dst + n * 4);
  float adh = (hh == 0) ? ad.x : (hh == 1) ? ad.y : (hh == 2) ? ad.z : ad.w;

  float acc, denom;
  {
    float4 as = *(const float4*)(a_src + n * 4);
    float ash = (hh == 0) ? as.x : (hh == 1) ? as.y : (hh == 2) ? as.z : as.w;
    float w = expf(leakyf(ash + adh));
    acc = w * hbuf[(size_t)n * HC + tid];
    denom = w;
  }
  int start = rowptr[n], end = rowptr[n + 1];
  for (int base = start; base < end; base += 64) {
    int m = end - base; m = m < 64 ? m : 64;
    __syncthreads();
    if (tid < m) {
      int s = ssrc[base + tid];
      s_idx[tid] = s;
      float4 as = *(const float4*)(a_src + s * 4);
      s_w[tid * 4 + 0] = expf(leakyf(as.x + ad.x));
      s_w[tid * 4 + 1] = expf(leakyf(as.y + ad.y));
      s_w[tid * 4 + 2] = expf(leakyf(as.z + ad.z));
      s_w[tid * 4 + 3] = expf(leakyf(as.w + ad.w));
    }
    __syncthreads();
    for (int i = 0; i < m; ++i) {
      float w = s_w[i * 4 + hh];
      acc = fmaf(w, hbuf[(size_t)s_idx[i] * HC + tid], acc);
      denom += w;
    }
  }
  s_res[tid] = acc / (denom + 1e-16f);
  __syncthreads();
  if (tid < CC) {
    float v = 0.25f * (s_res[tid] + s_res[tid + 128] + s_res[tid + 256] + s_res[tid + 384]) + b_gat[tid];
    y[(size_t)n * CC + tid] = leakyf(v);
  }
}

// ---------------------------------------------------------------------------
// z = leaky(y @ W1 + b1), W1 staged in LDS, 2 nodes per block-iteration
// ---------------------------------------------------------------------------
__global__ __launch_bounds__(256) void linear_kernel(const float* __restrict__ y,
    const float* __restrict__ W1, const float* __restrict__ b1, float* __restrict__ z) {
  __shared__ float sW[NHID * CC];   // 64 KB
  __shared__ float sy[2][CC];
  const int tid = threadIdx.x;
  const int j = tid & 127;
  const int p = tid >> 7;
  for (int idx = tid * 4; idx < NHID * CC; idx += 1024)
    *(float4*)&sW[idx] = *(const float4*)&W1[idx];
  float bj = b1[j];
  __syncthreads();
  for (int n0 = blockIdx.x * 2; n0 < N_NODES; n0 += gridDim.x * 2) {
    int n = n0 + p;
    sy[p][j] = y[(size_t)n * CC + j];
    __syncthreads();
    float acc = bj;
#pragma unroll 8
    for (int i = 0; i < CC; i += 4) {
      float4 yv = *(const float4*)&sy[p][i];
      acc = fmaf(yv.x, sW[(i + 0) * CC + j], acc);
      acc = fmaf(yv.y, sW[(i + 1) * CC + j], acc);
      acc = fmaf(yv.z, sW[(i + 2) * CC + j], acc);
      acc = fmaf(yv.w, sW[(i + 3) * CC + j], acc);
    }
    z[(size_t)n * CC + j] = leakyf(acc);
    __syncthreads();
  }
}

// ---------------------------------------------------------------------------
// final: logits = z_flat[N,1024] @ W2[1024,2] + b2 ; log_softmax. one wave/node
// ---------------------------------------------------------------------------
__global__ void final_kernel(const float* __restrict__ z, const float* __restrict__ W2,
                             const float* __restrict__ b2, float* __restrict__ out) {
  int gw = (blockIdx.x * blockDim.x + threadIdx.x) >> 6;
  int lane = threadIdx.x & 63;
  if (gw >= N_NODES) return;
  const float* row = z + (size_t)gw * 1024;
  float a0 = 0.f, a1 = 0.f;
#pragma unroll
  for (int it = 0; it < 4; ++it) {
    int k = lane * 4 + it * 256;
    float4 v = *(const float4*)(row + k);
    float4 w01 = *(const float4*)(W2 + k * 2);
    float4 w23 = *(const float4*)(W2 + k * 2 + 4);
    a0 += v.x * w01.x + v.y * w01.z + v.z * w23.x + v.w * w23.z;
    a1 += v.x * w01.y + v.y * w01.w + v.z * w23.y + v.w * w23.w;
  }
#pragma unroll
  for (int off = 32; off; off >>= 1) {
    a0 += __shfl_down(a0, off);
    a1 += __shfl_down(a1, off);
  }
  if (lane == 0) {
    float l0 = a0 + b2[0], l1 = a1 + b2[1];
    float m = fmaxf(l0, l1);
    float lse = m + logf(expf(l0 - m) + expf(l1 - m));
    out[gw * 2 + 0] = l0 - lse;
    out[gw * 2 + 1] = l1 - lse;
  }
}

// ---------------------------------------------------------------------------
extern "C" void kernel_launch(void* const* d_in, const int* in_sizes, int n_in,
                              void* d_out, int out_size, void* d_ws, size_t ws_size,
                              hipStream_t stream) {
  (void)in_sizes; (void)n_in; (void)out_size; (void)ws_size;
  const float* fts    = (const float*)d_in[0];
  const int*   graph  = (const int*)d_in[1];
  const float* W_gat  = (const float*)d_in[3];
  const float* att_s  = (const float*)d_in[4];
  const float* att_d  = (const float*)d_in[5];
  const float* b_gat  = (const float*)d_in[6];
  const float* W1     = (const float*)d_in[7];
  const float* b1     = (const float*)d_in[8];
  const float* W2     = (const float*)d_in[9];
  const float* b2     = (const float*)d_in[10];
  float* out = (float*)d_out;

  char* ws = (char*)d_ws;
  size_t off = 0;
  auto alloc = [&](size_t bytes) -> void* {
    void* p = ws + off;
    off += (bytes + 255) & ~(size_t)255;
    return p;
  };
  float* h      = (float*)alloc((size_t)N_NODES * HC * 4);
  float* yb     = (float*)alloc((size_t)N_NODES * CC * 4);
  float* as_    = (float*)alloc((size_t)N_NODES * NH * 4);
  float* ad_    = (float*)alloc((size_t)N_NODES * NH * 4);
  int*   deg    = (int*)alloc((size_t)T_STEPS * N_NODES * 4);
  int*   rowptr = (int*)alloc((size_t)T_STEPS * (N_NODES + 1) * 4);
  int*   fill   = (int*)alloc((size_t)T_STEPS * N_NODES * 4);
  int*   ssrc   = (int*)alloc((size_t)T_STEPS * N_EDGES * 4);
  float* z      = (float*)alloc((size_t)T_STEPS * N_NODES * CC * 4);

  hipMemsetAsync(deg, 0, (size_t)T_STEPS * N_NODES * 4, stream);
  hipMemsetAsync(fill, 0, (size_t)T_STEPS * N_NODES * 4, stream);
  const int totE = T_STEPS * N_EDGES;
  count_kernel<<<(totE + 255) / 256, 256, 0, stream>>>(graph, deg);
  scan_kernel<<<T_STEPS, 1024, 0, stream>>>(deg, rowptr);
  scatter_kernel<<<(totE + 255) / 256, 256, 0, stream>>>(graph, rowptr, fill, ssrc);

  for (int t = 0; t < T_STEPS; ++t) {
    gemm_h<<<dim3(HC / BN, (N_NODES + BM - 1) / BM), 256, 0, stream>>>(
        fts + (size_t)t * N_NODES * NFEAT, W_gat, h);
    att_kernel<<<(N_NODES * NH + 255) / 256, 256, 0, stream>>>(h, att_s, att_d, as_, ad_);
    aggregate_kernel<<<N_NODES, 512, 0, stream>>>(
        h, as_, ad_, rowptr + t * (N_NODES + 1), ssrc + (size_t)t * N_EDGES, b_gat, yb);
    linear_kernel<<<512, 256, 0, stream>>>(yb, W1, b1, z + (size_t)t * N_NODES * CC);
  }
  final_kernel<<<(N_NODES * 64) / 256, 256, 0, stream>>>(z, W2, b2, out);
}

// Round 2
// 2273.183 us; speedup vs baseline: 1.3842x; 1.3842x over previous
//
#include <hip/hip_runtime.h>
#include <cstdint>
#include <cstddef>

#define N_NODES 20000
#define T_STEPS 8
#define N_EDGES 320000
#define NFEAT 512
#define HC 512      // H*C
#define NH 4
#define CC 128
#define NHID 128
#define SLOPE 0.2f

typedef unsigned short ushort_t;
typedef short bf16x8 __attribute__((ext_vector_type(8)));
typedef float f32x4 __attribute__((ext_vector_type(4)));

__device__ __forceinline__ float leakyf(float x) { return x >= 0.f ? x : SLOPE * x; }

__device__ __forceinline__ ushort_t f2bf_hi(float x) {
  union { float f; uint32_t u; } c; c.f = x;
  uint32_t r = c.u + 0x7FFFu + ((c.u >> 16) & 1u);
  return (ushort_t)(r >> 16);
}
__device__ __forceinline__ float bfbits2f(ushort_t b) {
  union { float f; uint32_t u; } c; c.u = (uint32_t)b << 16; return c.f;
}

// ---------------------------------------------------------------------------
// one-time: W_gat [512 k][512 n] fp32 -> Bt_hi/Bt_lo [n][k] bf16 (split)
// ---------------------------------------------------------------------------
__global__ void bsplit_kernel(const float* __restrict__ W,
                              ushort_t* __restrict__ Bh, ushort_t* __restrict__ Bl) {
  int idx = blockIdx.x * blockDim.x + threadIdx.x;
  if (idx >= HC * NFEAT) return;
  int n = idx >> 9, k = idx & 511;
  float v = W[(size_t)k * HC + n];
  ushort_t h = f2bf_hi(v);
  Bh[idx] = h;
  Bl[idx] = f2bf_hi(v - bfbits2f(h));
}

// ---------------------------------------------------------------------------
// GEMM: C[160000,512] = A[160000,512]fp32 @ B[512,512] via split-bf16 MFMA
// 128x128 tile, BK=32, 4 waves of 64x64, 16x16x32 bf16 MFMA, 3 products
// ---------------------------------------------------------------------------
__global__ __launch_bounds__(256) void gemm_mfma(const float* __restrict__ A,
    const ushort_t* __restrict__ Bth, const ushort_t* __restrict__ Btl,
    float* __restrict__ C) {
  // [buf][plane hi/lo][kgroup 0..3][row 0..127][8 bf16]  (16 B per row-chunk)
  __shared__ ushort_t As[2][2][4][128][8];
  __shared__ ushort_t Bs[2][2][4][128][8];
  const int tid = threadIdx.x;
  const int lane = tid & 63;
  const int wave = tid >> 6;
  const int wm = wave >> 1, wn = wave & 1;
  const size_t row0 = (size_t)blockIdx.y * 128;
  const int col0 = blockIdx.x * 128;
  const int ar = tid >> 3, ac4 = tid & 7;          // A stage: row base, float4 idx
  const int akg = ac4 >> 1, ah = (ac4 & 1) * 4;
  const int bn = tid >> 2, bch = tid & 3;          // B stage: n base, 16B chunk

  f32x4 acc[4][4];
#pragma unroll
  for (int i = 0; i < 4; ++i)
#pragma unroll
    for (int j = 0; j < 4; ++j) acc[i][j] = (f32x4){0.f, 0.f, 0.f, 0.f};

  float4 pa[4]; float4 pbh[2]; float4 pbl[2];

#define LOADG(ks_) do { \
    const int k0_ = (ks_) * 32; \
    _Pragma("unroll") \
    for (int f = 0; f < 4; ++f) \
      pa[f] = *(const float4*)(A + (row0 + ar + f * 32) * 512 + k0_ + ac4 * 4); \
    _Pragma("unroll") \
    for (int g = 0; g < 2; ++g) { \
      pbh[g] = *(const float4*)(Bth + (size_t)(col0 + bn + g * 64) * 512 + k0_ + bch * 8); \
      pbl[g] = *(const float4*)(Btl + (size_t)(col0 + bn + g * 64) * 512 + k0_ + bch * 8); \
    } \
  } while (0)

#define STORES(b_) do { \
    _Pragma("unroll") \
    for (int f = 0; f < 4; ++f) { \
      int r_ = ar + f * 32; \
      ushort_t h0 = f2bf_hi(pa[f].x), h1 = f2bf_hi(pa[f].y), h2 = f2bf_hi(pa[f].z), h3 = f2bf_hi(pa[f].w); \
      ushort_t l0 = f2bf_hi(pa[f].x - bfbits2f(h0)), l1 = f2bf_hi(pa[f].y - bfbits2f(h1)); \
      ushort_t l2 = f2bf_hi(pa[f].z - bfbits2f(h2)), l3 = f2bf_hi(pa[f].w - bfbits2f(h3)); \
      *(ushort4*)&As[b_][0][akg][r_][ah] = make_ushort4(h0, h1, h2, h3); \
      *(ushort4*)&As[b_][1][akg][r_][ah] = make_ushort4(l0, l1, l2, l3); \
    } \
    _Pragma("unroll") \
    for (int g = 0; g < 2; ++g) { \
      *(float4*)&Bs[b_][0][bch][bn + g * 64][0] = pbh[g]; \
      *(float4*)&Bs[b_][1][bch][bn + g * 64][0] = pbl[g]; \
    } \
  } while (0)

  LOADG(0);
  STORES(0);
  __syncthreads();

  for (int ks = 0; ks < 16; ++ks) {
    const int b = ks & 1;
    if (ks < 15) LOADG(ks + 1);

    bf16x8 af[4][2], bfr[4][2];
#pragma unroll
    for (int mi = 0; mi < 4; ++mi) {
      af[mi][0] = *(const bf16x8*)&As[b][0][lane >> 4][wm * 64 + mi * 16 + (lane & 15)][0];
      af[mi][1] = *(const bf16x8*)&As[b][1][lane >> 4][wm * 64 + mi * 16 + (lane & 15)][0];
    }
#pragma unroll
    for (int ni = 0; ni < 4; ++ni) {
      bfr[ni][0] = *(const bf16x8*)&Bs[b][0][lane >> 4][wn * 64 + ni * 16 + (lane & 15)][0];
      bfr[ni][1] = *(const bf16x8*)&Bs[b][1][lane >> 4][wn * 64 + ni * 16 + (lane & 15)][0];
    }
#pragma unroll
    for (int mi = 0; mi < 4; ++mi)
#pragma unroll
      for (int ni = 0; ni < 4; ++ni) {
        acc[mi][ni] = __builtin_amdgcn_mfma_f32_16x16x32_bf16(af[mi][0], bfr[ni][0], acc[mi][ni], 0, 0, 0);
        acc[mi][ni] = __builtin_amdgcn_mfma_f32_16x16x32_bf16(af[mi][0], bfr[ni][1], acc[mi][ni], 0, 0, 0);
        acc[mi][ni] = __builtin_amdgcn_mfma_f32_16x16x32_bf16(af[mi][1], bfr[ni][0], acc[mi][ni], 0, 0, 0);
      }
    if (ks < 15) {
      __syncthreads();
      STORES(b ^ 1);
      __syncthreads();
    }
  }
#undef LOADG
#undef STORES

#pragma unroll
  for (int mi = 0; mi < 4; ++mi) {
    const size_t rb = row0 + wm * 64 + mi * 16 + (lane >> 4) * 4;
#pragma unroll
    for (int ni = 0; ni < 4; ++ni) {
      const int cb = col0 + wn * 64 + ni * 16 + (lane & 15);
#pragma unroll
      for (int r = 0; r < 4; ++r)
        C[(rb + r) * 512 + cb] = acc[mi][ni][r];
    }
  }
}

// ---------------------------------------------------------------------------
// per-(t,node,head) attention logits (batched over T)
// ---------------------------------------------------------------------------
__global__ void att_kernel(const float* __restrict__ hbuf,
                           const float* __restrict__ att_src,
                           const float* __restrict__ att_dst,
                           float* __restrict__ a_src, float* __restrict__ a_dst) {
  int idx = blockIdx.x * blockDim.x + threadIdx.x;
  if (idx >= T_STEPS * N_NODES * NH) return;
  int n = idx >> 2, hh = idx & 3;
  const float* hp = hbuf + (size_t)n * HC + hh * CC;
  const float* ps = att_src + hh * CC;
  const float* pd = att_dst + hh * CC;
  float s = 0.f, d = 0.f;
#pragma unroll 4
  for (int c = 0; c < CC; c += 4) {
    float4 hv = *(const float4*)(hp + c);
    float4 sv = *(const float4*)(ps + c);
    float4 dv = *(const float4*)(pd + c);
    s += hv.x * sv.x + hv.y * sv.y + hv.z * sv.z + hv.w * sv.w;
    d += hv.x * dv.x + hv.y * dv.y + hv.z * dv.z + hv.w * dv.w;
  }
  a_src[idx] = s;
  a_dst[idx] = d;
}

// ---------------------------------------------------------------------------
// CSR build (all T at once)
// ---------------------------------------------------------------------------
__global__ void count_kernel(const int* __restrict__ graph, int* __restrict__ deg) {
  int idx = blockIdx.x * blockDim.x + threadIdx.x;
  if (idx >= T_STEPS * N_EDGES) return;
  int t = idx / N_EDGES, e = idx - t * N_EDGES;
  int d = graph[(size_t)t * 2 * N_EDGES + N_EDGES + e];
  atomicAdd(&deg[t * N_NODES + d], 1);
}

__global__ __launch_bounds__(1024) void scan_kernel(const int* __restrict__ deg,
                                                    int* __restrict__ rowptr) {
  int t = blockIdx.x;
  const int* dp = deg + t * N_NODES;
  int* rp = rowptr + t * (N_NODES + 1);
  __shared__ int s_sums[16];
  __shared__ int s_carry;
  int lane = threadIdx.x & 63;
  int wid = threadIdx.x >> 6;
  if (threadIdx.x == 0) { s_carry = 0; rp[0] = 0; }
  __syncthreads();
  for (int base = 0; base < N_NODES; base += 1024) {
    int i = base + threadIdx.x;
    int v = (i < N_NODES) ? dp[i] : 0;
    int x = v;
#pragma unroll
    for (int off = 1; off < 64; off <<= 1) {
      int y = __shfl_up(x, off);
      if (lane >= off) x += y;
    }
    if (lane == 63) s_sums[wid] = x;
    __syncthreads();
    if (threadIdx.x < 16) {
      int ws = s_sums[threadIdx.x];
#pragma unroll
      for (int off = 1; off < 16; off <<= 1) {
        int y = __shfl_up(ws, off);
        if (threadIdx.x >= off) ws += y;
      }
      s_sums[threadIdx.x] = ws;
    }
    __syncthreads();
    int add = s_carry + (wid > 0 ? s_sums[wid - 1] : 0);
    if (i < N_NODES) rp[i + 1] = x + add;
    __syncthreads();
    if (threadIdx.x == 0) s_carry += s_sums[15];
    __syncthreads();
  }
}

__global__ void scatter_kernel(const int* __restrict__ graph, const int* __restrict__ rowptr,
                               int* __restrict__ fill, int* __restrict__ ssrc) {
  int idx = blockIdx.x * blockDim.x + threadIdx.x;
  if (idx >= T_STEPS * N_EDGES) return;
  int t = idx / N_EDGES, e = idx - t * N_EDGES;
  const int* g = graph + (size_t)t * 2 * N_EDGES;
  int s = g[e], d = g[N_EDGES + e];
  int pos = rowptr[t * (N_NODES + 1) + d] + atomicAdd(&fill[t * N_NODES + d], 1);
  ssrc[(size_t)t * N_EDGES + pos] = s;
}

// ---------------------------------------------------------------------------
// GAT aggregation: block = (node, t), 512 threads (one per h*c element)
// ---------------------------------------------------------------------------
__global__ __launch_bounds__(512) void aggregate_kernel(const float* __restrict__ h_all,
    const float* __restrict__ as_all, const float* __restrict__ ad_all,
    const int* __restrict__ rowptr_all, const int* __restrict__ ssrc_all,
    const float* __restrict__ b_gat, float* __restrict__ y_all) {
  const int n = blockIdx.x;
  const int t = blockIdx.y;
  const float* hbuf = h_all + (size_t)t * N_NODES * HC;
  const float* a_src = as_all + (size_t)t * N_NODES * NH;
  const float* a_dst = ad_all + (size_t)t * N_NODES * NH;
  const int* rowptr = rowptr_all + t * (N_NODES + 1);
  const int* ssrc = ssrc_all + (size_t)t * N_EDGES;
  float* y = y_all + (size_t)t * N_NODES * CC;

  const int tid = threadIdx.x;
  const int hh = tid >> 7;
  __shared__ int s_idx[64];
  __shared__ float s_w[64 * 4];
  __shared__ float s_res[512];

  float4 ad = *(const float4*)(a_dst + n * 4);
  float adh = (hh == 0) ? ad.x : (hh == 1) ? ad.y : (hh == 2) ? ad.z : ad.w;

  float acc, denom;
  {
    float4 as = *(const float4*)(a_src + n * 4);
    float ash = (hh == 0) ? as.x : (hh == 1) ? as.y : (hh == 2) ? as.z : as.w;
    float w = expf(leakyf(ash + adh));
    acc = w * hbuf[(size_t)n * HC + tid];
    denom = w;
  }
  int start = rowptr[n], end = rowptr[n + 1];
  for (int base = start; base < end; base += 64) {
    int m = end - base; m = m < 64 ? m : 64;
    __syncthreads();
    if (tid < m) {
      int s = ssrc[base + tid];
      s_idx[tid] = s;
      float4 as = *(const float4*)(a_src + s * 4);
      s_w[tid * 4 + 0] = expf(leakyf(as.x + ad.x));
      s_w[tid * 4 + 1] = expf(leakyf(as.y + ad.y));
      s_w[tid * 4 + 2] = expf(leakyf(as.z + ad.z));
      s_w[tid * 4 + 3] = expf(leakyf(as.w + ad.w));
    }
    __syncthreads();
    for (int i = 0; i < m; ++i) {
      float w = s_w[i * 4 + hh];
      acc = fmaf(w, hbuf[(size_t)s_idx[i] * HC + tid], acc);
      denom += w;
    }
  }
  s_res[tid] = acc / (denom + 1e-16f);
  __syncthreads();
  if (tid < CC) {
    float v = 0.25f * (s_res[tid] + s_res[tid + 128] + s_res[tid + 256] + s_res[tid + 384]) + b_gat[tid];
    y[(size_t)n * CC + tid] = leakyf(v);
  }
}

// ---------------------------------------------------------------------------
// z = leaky(y @ W1 + b1), batched over all T*N rows, W1 in LDS
// ---------------------------------------------------------------------------
__global__ __launch_bounds__(256) void linear_kernel(const float* __restrict__ y,
    const float* __restrict__ W1, const float* __restrict__ b1, float* __restrict__ z) {
  __shared__ float sW[NHID * CC];   // 64 KB
  __shared__ float sy[2][CC];
  const int tid = threadIdx.x;
  const int j = tid & 127;
  const int p = tid >> 7;
  for (int idx = tid * 4; idx < NHID * CC; idx += 1024)
    *(float4*)&sW[idx] = *(const float4*)&W1[idx];
  float bj = b1[j];
  __syncthreads();
  const int TOT = T_STEPS * N_NODES;
  for (int n0 = blockIdx.x * 2; n0 < TOT; n0 += gridDim.x * 2) {
    int n = n0 + p;
    sy[p][j] = y[(size_t)n * CC + j];
    __syncthreads();
    float acc = bj;
#pragma unroll 8
    for (int i = 0; i < CC; i += 4) {
      float4 yv = *(const float4*)&sy[p][i];
      acc = fmaf(yv.x, sW[(i + 0) * CC + j], acc);
      acc = fmaf(yv.y, sW[(i + 1) * CC + j], acc);
      acc = fmaf(yv.z, sW[(i + 2) * CC + j], acc);
      acc = fmaf(yv.w, sW[(i + 3) * CC + j], acc);
    }
    z[(size_t)n * CC + j] = leakyf(acc);
    __syncthreads();
  }
}

// ---------------------------------------------------------------------------
// final: logits = z_flat[N,1024] @ W2[1024,2] + b2 ; log_softmax. one wave/node
// ---------------------------------------------------------------------------
__global__ void final_kernel(const float* __restrict__ z, const float* __restrict__ W2,
                             const float* __restrict__ b2, float* __restrict__ out) {
  int gw = (blockIdx.x * blockDim.x + threadIdx.x) >> 6;
  int lane = threadIdx.x & 63;
  if (gw >= N_NODES) return;
  const float* row = z + (size_t)gw * 1024;
  float a0 = 0.f, a1 = 0.f;
#pragma unroll
  for (int it = 0; it < 4; ++it) {
    int k = lane * 4 + it * 256;
    float4 v = *(const float4*)(row + k);
    float4 w01 = *(const float4*)(W2 + k * 2);
    float4 w23 = *(const float4*)(W2 + k * 2 + 4);
    a0 += v.x * w01.x + v.y * w01.z + v.z * w23.x + v.w * w23.z;
    a1 += v.x * w01.y + v.y * w01.w + v.z * w23.y + v.w * w23.w;
  }
#pragma unroll
  for (int off = 32; off; off >>= 1) {
    a0 += __shfl_down(a0, off);
    a1 += __shfl_down(a1, off);
  }
  if (lane == 0) {
    float l0 = a0 + b2[0], l1 = a1 + b2[1];
    float m = fmaxf(l0, l1);
    float lse = m + logf(expf(l0 - m) + expf(l1 - m));
    out[gw * 2 + 0] = l0 - lse;
    out[gw * 2 + 1] = l1 - lse;
  }
}

// ---------------------------------------------------------------------------
extern "C" void kernel_launch(void* const* d_in, const int* in_sizes, int n_in,
                              void* d_out, int out_size, void* d_ws, size_t ws_size,
                              hipStream_t stream) {
  (void)in_sizes; (void)n_in; (void)out_size; (void)ws_size;
  const float* fts    = (const float*)d_in[0];
  const int*   graph  = (const int*)d_in[1];
  const float* W_gat  = (const float*)d_in[3];
  const float* att_s  = (const float*)d_in[4];
  const float* att_d  = (const float*)d_in[5];
  const float* b_gat  = (const float*)d_in[6];
  const float* W1     = (const float*)d_in[7];
  const float* b1     = (const float*)d_in[8];
  const float* W2     = (const float*)d_in[9];
  const float* b2     = (const float*)d_in[10];
  float* out = (float*)d_out;

  char* ws = (char*)d_ws;
  size_t off = 0;
  auto alloc = [&](size_t bytes) -> void* {
    void* p = ws + off;
    off += (bytes + 255) & ~(size_t)255;
    return p;
  };
  const size_t TN = (size_t)T_STEPS * N_NODES;
  float*    h_all  = (float*)alloc(TN * HC * 4);        // 327.7 MB
  float*    yb_all = (float*)alloc(TN * CC * 4);        // 81.9 MB
  float*    z      = (float*)alloc(TN * CC * 4);        // 81.9 MB
  float*    as_    = (float*)alloc(TN * NH * 4);
  float*    ad_    = (float*)alloc(TN * NH * 4);
  int*      deg    = (int*)alloc((size_t)T_STEPS * N_NODES * 4);
  int*      rowptr = (int*)alloc((size_t)T_STEPS * (N_NODES + 1) * 4);
  int*      fill   = (int*)alloc((size_t)T_STEPS * N_NODES * 4);
  int*      ssrc   = (int*)alloc((size_t)T_STEPS * N_EDGES * 4);
  ushort_t* Bth    = (ushort_t*)alloc((size_t)HC * NFEAT * 2);
  ushort_t* Btl    = (ushort_t*)alloc((size_t)HC * NFEAT * 2);

  hipMemsetAsync(deg, 0, (size_t)T_STEPS * N_NODES * 4, stream);
  hipMemsetAsync(fill, 0, (size_t)T_STEPS * N_NODES * 4, stream);

  const int totE = T_STEPS * N_EDGES;
  count_kernel<<<(totE + 255) / 256, 256, 0, stream>>>(graph, deg);
  scan_kernel<<<T_STEPS, 1024, 0, stream>>>(deg, rowptr);
  scatter_kernel<<<(totE + 255) / 256, 256, 0, stream>>>(graph, rowptr, fill, ssrc);

  bsplit_kernel<<<(HC * NFEAT + 255) / 256, 256, 0, stream>>>(W_gat, Bth, Btl);

  // one fused GEMM over all T: [160000, 512] @ [512, 512]
  gemm_mfma<<<dim3(HC / 128, (int)(TN / 128)), 256, 0, stream>>>(fts, Bth, Btl, h_all);

  att_kernel<<<(int)((TN * NH + 255) / 256), 256, 0, stream>>>(h_all, att_s, att_d, as_, ad_);

  aggregate_kernel<<<dim3(N_NODES, T_STEPS), 512, 0, stream>>>(
      h_all, as_, ad_, rowptr, ssrc, b_gat, yb_all);

  linear_kernel<<<2048, 256, 0, stream>>>(yb_all, W1, b1, z);

  final_kernel<<<(N_NODES * 64) / 256, 256, 0, stream>>>(z, W2, b2, out);
}

// Round 3
// 1754.862 us; speedup vs baseline: 1.7930x; 1.2954x over previous
//
#include <hip/hip_runtime.h>
#include <cstdint>
#include <cstddef>

#define N_NODES 20000
#define T_STEPS 8
#define N_EDGES 320000
#define NFEAT 512
#define HC 512      // H*C
#define NH 4
#define CC 128
#define NHID 128
#define SLOPE 0.2f

typedef unsigned short ushort_t;
typedef short bf16x8 __attribute__((ext_vector_type(8)));
typedef float f32x4 __attribute__((ext_vector_type(4)));

__device__ __forceinline__ float leakyf(float x) { return x >= 0.f ? x : SLOPE * x; }

__device__ __forceinline__ ushort_t f2bf_hi(float x) {
  union { float f; uint32_t u; } c; c.f = x;
  uint32_t r = c.u + 0x7FFFu + ((c.u >> 16) & 1u);
  return (ushort_t)(r >> 16);
}
__device__ __forceinline__ float bfbits2f(ushort_t b) {
  union { float f; uint32_t u; } c; c.u = (uint32_t)b << 16; return c.f;
}

// ---------------------------------------------------------------------------
// one-time: W_gat [512 k][512 n] fp32 -> Bt_hi/Bt_lo [n][k] bf16 (split)
// ---------------------------------------------------------------------------
__global__ void bsplit_kernel(const float* __restrict__ W,
                              ushort_t* __restrict__ Bh, ushort_t* __restrict__ Bl) {
  int idx = blockIdx.x * blockDim.x + threadIdx.x;
  if (idx >= HC * NFEAT) return;
  int n = idx >> 9, k = idx & 511;
  float v = W[(size_t)k * HC + n];
  ushort_t h = f2bf_hi(v);
  Bh[idx] = h;
  Bl[idx] = f2bf_hi(v - bfbits2f(h));
}

// ---------------------------------------------------------------------------
// GEMM: C[160000,512](bf16) = A[160000,512]fp32 @ B[512,512] via split-bf16 MFMA
// 128x128 tile, BK=32, 4 waves of 64x64, 16x16x32 bf16 MFMA, 3 products
// ---------------------------------------------------------------------------
__global__ __launch_bounds__(256) void gemm_mfma(const float* __restrict__ A,
    const ushort_t* __restrict__ Bth, const ushort_t* __restrict__ Btl,
    ushort_t* __restrict__ C) {
  // [buf][plane hi/lo][kgroup 0..3][row 0..127][8 bf16]  (16 B per row-chunk)
  __shared__ ushort_t As[2][2][4][128][8];
  __shared__ ushort_t Bs[2][2][4][128][8];
  const int tid = threadIdx.x;
  const int lane = tid & 63;
  const int wave = tid >> 6;
  const int wm = wave >> 1, wn = wave & 1;
  const size_t row0 = (size_t)blockIdx.y * 128;
  const int col0 = blockIdx.x * 128;
  const int ar = tid >> 3, ac4 = tid & 7;          // A stage: row base, float4 idx
  const int akg = ac4 >> 1, ah = (ac4 & 1) * 4;
  const int bn = tid >> 2, bch = tid & 3;          // B stage: n base, 16B chunk

  f32x4 acc[4][4];
#pragma unroll
  for (int i = 0; i < 4; ++i)
#pragma unroll
    for (int j = 0; j < 4; ++j) acc[i][j] = (f32x4){0.f, 0.f, 0.f, 0.f};

  float4 pa[4]; float4 pbh[2]; float4 pbl[2];

#define LOADG(ks_) do { \
    const int k0_ = (ks_) * 32; \
    _Pragma("unroll") \
    for (int f = 0; f < 4; ++f) \
      pa[f] = *(const float4*)(A + (row0 + ar + f * 32) * 512 + k0_ + ac4 * 4); \
    _Pragma("unroll") \
    for (int g = 0; g < 2; ++g) { \
      pbh[g] = *(const float4*)(Bth + (size_t)(col0 + bn + g * 64) * 512 + k0_ + bch * 8); \
      pbl[g] = *(const float4*)(Btl + (size_t)(col0 + bn + g * 64) * 512 + k0_ + bch * 8); \
    } \
  } while (0)

#define STORES(b_) do { \
    _Pragma("unroll") \
    for (int f = 0; f < 4; ++f) { \
      int r_ = ar + f * 32; \
      ushort_t h0 = f2bf_hi(pa[f].x), h1 = f2bf_hi(pa[f].y), h2 = f2bf_hi(pa[f].z), h3 = f2bf_hi(pa[f].w); \
      ushort_t l0 = f2bf_hi(pa[f].x - bfbits2f(h0)), l1 = f2bf_hi(pa[f].y - bfbits2f(h1)); \
      ushort_t l2 = f2bf_hi(pa[f].z - bfbits2f(h2)), l3 = f2bf_hi(pa[f].w - bfbits2f(h3)); \
      *(ushort4*)&As[b_][0][akg][r_][ah] = make_ushort4(h0, h1, h2, h3); \
      *(ushort4*)&As[b_][1][akg][r_][ah] = make_ushort4(l0, l1, l2, l3); \
    } \
    _Pragma("unroll") \
    for (int g = 0; g < 2; ++g) { \
      *(float4*)&Bs[b_][0][bch][bn + g * 64][0] = pbh[g]; \
      *(float4*)&Bs[b_][1][bch][bn + g * 64][0] = pbl[g]; \
    } \
  } while (0)

  LOADG(0);
  STORES(0);
  __syncthreads();

  for (int ks = 0; ks < 16; ++ks) {
    const int b = ks & 1;
    if (ks < 15) LOADG(ks + 1);

    bf16x8 af[4][2], bfr[4][2];
#pragma unroll
    for (int mi = 0; mi < 4; ++mi) {
      af[mi][0] = *(const bf16x8*)&As[b][0][lane >> 4][wm * 64 + mi * 16 + (lane & 15)][0];
      af[mi][1] = *(const bf16x8*)&As[b][1][lane >> 4][wm * 64 + mi * 16 + (lane & 15)][0];
    }
#pragma unroll
    for (int ni = 0; ni < 4; ++ni) {
      bfr[ni][0] = *(const bf16x8*)&Bs[b][0][lane >> 4][wn * 64 + ni * 16 + (lane & 15)][0];
      bfr[ni][1] = *(const bf16x8*)&Bs[b][1][lane >> 4][wn * 64 + ni * 16 + (lane & 15)][0];
    }
#pragma unroll
    for (int mi = 0; mi < 4; ++mi)
#pragma unroll
      for (int ni = 0; ni < 4; ++ni) {
        acc[mi][ni] = __builtin_amdgcn_mfma_f32_16x16x32_bf16(af[mi][0], bfr[ni][0], acc[mi][ni], 0, 0, 0);
        acc[mi][ni] = __builtin_amdgcn_mfma_f32_16x16x32_bf16(af[mi][0], bfr[ni][1], acc[mi][ni], 0, 0, 0);
        acc[mi][ni] = __builtin_amdgcn_mfma_f32_16x16x32_bf16(af[mi][1], bfr[ni][0], acc[mi][ni], 0, 0, 0);
      }
    if (ks < 15) {
      __syncthreads();
      STORES(b ^ 1);
      __syncthreads();
    }
  }
#undef LOADG
#undef STORES

#pragma unroll
  for (int mi = 0; mi < 4; ++mi) {
    const size_t rb = row0 + wm * 64 + mi * 16 + (lane >> 4) * 4;
#pragma unroll
    for (int ni = 0; ni < 4; ++ni) {
      const int cb = col0 + wn * 64 + ni * 16 + (lane & 15);
#pragma unroll
      for (int r = 0; r < 4; ++r)
        C[(rb + r) * 512 + cb] = f2bf_hi(acc[mi][ni][r]);
    }
  }
}

// ---------------------------------------------------------------------------
// attention logits: one wave per (t,node) row; lane covers 8 channels
// ---------------------------------------------------------------------------
__global__ __launch_bounds__(256) void att_kernel(const ushort_t* __restrict__ h_bf,
    const float* __restrict__ att_src, const float* __restrict__ att_dst,
    float* __restrict__ a_src, float* __restrict__ a_dst) {
  const size_t node = (size_t)blockIdx.x * 4 + (threadIdx.x >> 6);
  const int lane = threadIdx.x & 63;
  const int hh = lane >> 4;
  const int c0 = (lane & 15) * 8;
  const ushort_t* hp = h_bf + node * 512 + hh * 128 + c0;
  ushort4 p0 = *(const ushort4*)(hp);
  ushort4 p1 = *(const ushort4*)(hp + 4);
  const float* ps = att_src + hh * 128 + c0;
  const float* pd = att_dst + hh * 128 + c0;
  float4 s0 = *(const float4*)(ps), s1 = *(const float4*)(ps + 4);
  float4 d0 = *(const float4*)(pd), d1 = *(const float4*)(pd + 4);
  float s = bfbits2f(p0.x) * s0.x + bfbits2f(p0.y) * s0.y + bfbits2f(p0.z) * s0.z + bfbits2f(p0.w) * s0.w
          + bfbits2f(p1.x) * s1.x + bfbits2f(p1.y) * s1.y + bfbits2f(p1.z) * s1.z + bfbits2f(p1.w) * s1.w;
  float d = bfbits2f(p0.x) * d0.x + bfbits2f(p0.y) * d0.y + bfbits2f(p0.z) * d0.z + bfbits2f(p0.w) * d0.w
          + bfbits2f(p1.x) * d1.x + bfbits2f(p1.y) * d1.y + bfbits2f(p1.z) * d1.z + bfbits2f(p1.w) * d1.w;
#pragma unroll
  for (int off = 1; off < 16; off <<= 1) {
    s += __shfl_xor(s, off);
    d += __shfl_xor(d, off);
  }
  if ((lane & 15) == 0) {
    a_src[node * 4 + hh] = s;
    a_dst[node * 4 + hh] = d;
  }
}

// ---------------------------------------------------------------------------
// CSR build (all T at once)
// ---------------------------------------------------------------------------
__global__ void count_kernel(const int* __restrict__ graph, int* __restrict__ deg) {
  int idx = blockIdx.x * blockDim.x + threadIdx.x;
  if (idx >= T_STEPS * N_EDGES) return;
  int t = idx / N_EDGES, e = idx - t * N_EDGES;
  int d = graph[(size_t)t * 2 * N_EDGES + N_EDGES + e];
  atomicAdd(&deg[t * N_NODES + d], 1);
}

__global__ __launch_bounds__(1024) void scan_kernel(const int* __restrict__ deg,
                                                    int* __restrict__ rowptr) {
  int t = blockIdx.x;
  const int* dp = deg + t * N_NODES;
  int* rp = rowptr + t * (N_NODES + 1);
  __shared__ int s_sums[16];
  __shared__ int s_carry;
  int lane = threadIdx.x & 63;
  int wid = threadIdx.x >> 6;
  if (threadIdx.x == 0) { s_carry = 0; rp[0] = 0; }
  __syncthreads();
  for (int base = 0; base < N_NODES; base += 1024) {
    int i = base + threadIdx.x;
    int v = (i < N_NODES) ? dp[i] : 0;
    int x = v;
#pragma unroll
    for (int off = 1; off < 64; off <<= 1) {
      int y = __shfl_up(x, off);
      if (lane >= off) x += y;
    }
    if (lane == 63) s_sums[wid] = x;
    __syncthreads();
    if (threadIdx.x < 16) {
      int ws = s_sums[threadIdx.x];
#pragma unroll
      for (int off = 1; off < 16; off <<= 1) {
        int y = __shfl_up(ws, off);
        if (threadIdx.x >= off) ws += y;
      }
      s_sums[threadIdx.x] = ws;
    }
    __syncthreads();
    int add = s_carry + (wid > 0 ? s_sums[wid - 1] : 0);
    if (i < N_NODES) rp[i + 1] = x + add;
    __syncthreads();
    if (threadIdx.x == 0) s_carry += s_sums[15];
    __syncthreads();
  }
}

__global__ void scatter_kernel(const int* __restrict__ graph, const int* __restrict__ rowptr,
                               int* __restrict__ fill, int* __restrict__ ssrc) {
  int idx = blockIdx.x * blockDim.x + threadIdx.x;
  if (idx >= T_STEPS * N_EDGES) return;
  int t = idx / N_EDGES, e = idx - t * N_EDGES;
  const int* g = graph + (size_t)t * 2 * N_EDGES;
  int s = g[e], d = g[N_EDGES + e];
  int pos = rowptr[t * (N_NODES + 1) + d] + atomicAdd(&fill[t * N_NODES + d], 1);
  ssrc[(size_t)t * N_EDGES + pos] = s;
}

// ---------------------------------------------------------------------------
// GAT aggregation: block = (node, t), 256 threads, ushort2 (2 channels)/thread
// ---------------------------------------------------------------------------
__global__ __launch_bounds__(256) void aggregate_kernel(const ushort_t* __restrict__ h_all,
    const float* __restrict__ as_all, const float* __restrict__ ad_all,
    const int* __restrict__ rowptr_all, const int* __restrict__ ssrc_all,
    const float* __restrict__ b_gat, float* __restrict__ y_all) {
  const int n = blockIdx.x;
  const int t = blockIdx.y;
  const ushort_t* hbuf = h_all + (size_t)t * N_NODES * HC;
  const float* a_src = as_all + (size_t)t * N_NODES * NH;
  const float* a_dst = ad_all + (size_t)t * N_NODES * NH;
  const int* rowptr = rowptr_all + t * (N_NODES + 1);
  const int* ssrc = ssrc_all + (size_t)t * N_EDGES;
  float* y = y_all + (size_t)t * N_NODES * CC;

  const int tid = threadIdx.x;
  const int hh = tid >> 6;
  __shared__ int s_idx[64];
  __shared__ float s_w[64 * 4];
  __shared__ float2 s_res[256];

  float4 ad = *(const float4*)(a_dst + n * 4);
  float adh = (hh == 0) ? ad.x : (hh == 1) ? ad.y : (hh == 2) ? ad.z : ad.w;

  float acc0, acc1, denom;
  {
    float4 as = *(const float4*)(a_src + n * 4);
    float ash = (hh == 0) ? as.x : (hh == 1) ? as.y : (hh == 2) ? as.z : as.w;
    float w = expf(leakyf(ash + adh));
    ushort2 hv = *(const ushort2*)(hbuf + (size_t)n * HC + tid * 2);
    acc0 = w * bfbits2f(hv.x);
    acc1 = w * bfbits2f(hv.y);
    denom = w;
  }
  int start = rowptr[n], end = rowptr[n + 1];
  for (int base = start; base < end; base += 64) {
    int m = end - base; m = m < 64 ? m : 64;
    __syncthreads();
    if (tid < m) {
      int s = ssrc[base + tid];
      s_idx[tid] = s;
      float4 as = *(const float4*)(a_src + s * 4);
      s_w[tid * 4 + 0] = expf(leakyf(as.x + ad.x));
      s_w[tid * 4 + 1] = expf(leakyf(as.y + ad.y));
      s_w[tid * 4 + 2] = expf(leakyf(as.z + ad.z));
      s_w[tid * 4 + 3] = expf(leakyf(as.w + ad.w));
    }
    __syncthreads();
    for (int i = 0; i < m; ++i) {
      float w = s_w[i * 4 + hh];
      ushort2 hv = *(const ushort2*)(hbuf + (size_t)s_idx[i] * HC + tid * 2);
      acc0 = fmaf(w, bfbits2f(hv.x), acc0);
      acc1 = fmaf(w, bfbits2f(hv.y), acc1);
      denom += w;
    }
  }
  float inv = 1.f / (denom + 1e-16f);
  s_res[tid] = make_float2(acc0 * inv, acc1 * inv);
  __syncthreads();
  if (tid < 64) {
    float2 A = s_res[tid], B = s_res[tid + 64], Cv = s_res[tid + 128], D = s_res[tid + 192];
    float2 bg = *(const float2*)(b_gat + tid * 2);
    float2 v;
    v.x = leakyf(0.25f * (A.x + B.x + Cv.x + D.x) + bg.x);
    v.y = leakyf(0.25f * (A.y + B.y + Cv.y + D.y) + bg.y);
    *(float2*)(y + (size_t)n * CC + tid * 2) = v;
  }
}

// ---------------------------------------------------------------------------
// z = leaky(y @ W1 + b1), batched over all T*N rows, W1 in LDS
// ---------------------------------------------------------------------------
__global__ __launch_bounds__(256) void linear_kernel(const float* __restrict__ y,
    const float* __restrict__ W1, const float* __restrict__ b1, float* __restrict__ z) {
  __shared__ float sW[NHID * CC];   // 64 KB
  __shared__ float sy[2][CC];
  const int tid = threadIdx.x;
  const int j = tid & 127;
  const int p = tid >> 7;
  for (int idx = tid * 4; idx < NHID * CC; idx += 1024)
    *(float4*)&sW[idx] = *(const float4*)&W1[idx];
  float bj = b1[j];
  __syncthreads();
  const int TOT = T_STEPS * N_NODES;
  for (int n0 = blockIdx.x * 2; n0 < TOT; n0 += gridDim.x * 2) {
    int n = n0 + p;
    sy[p][j] = y[(size_t)n * CC + j];
    __syncthreads();
    float acc = bj;
#pragma unroll 8
    for (int i = 0; i < CC; i += 4) {
      float4 yv = *(const float4*)&sy[p][i];
      acc = fmaf(yv.x, sW[(i + 0) * CC + j], acc);
      acc = fmaf(yv.y, sW[(i + 1) * CC + j], acc);
      acc = fmaf(yv.z, sW[(i + 2) * CC + j], acc);
      acc = fmaf(yv.w, sW[(i + 3) * CC + j], acc);
    }
    z[(size_t)n * CC + j] = leakyf(acc);
    __syncthreads();
  }
}

// ---------------------------------------------------------------------------
// final: logits = z_flat[20000,1024] @ W2[1024,2] + b2 ; log_softmax. one wave/row
// (z flat order [t][n][j] equals the reference's faithful-reshape row order)
// ---------------------------------------------------------------------------
__global__ void final_kernel(const float* __restrict__ z, const float* __restrict__ W2,
                             const float* __restrict__ b2, float* __restrict__ out) {
  int gw = (blockIdx.x * blockDim.x + threadIdx.x) >> 6;
  int lane = threadIdx.x & 63;
  if (gw >= N_NODES) return;
  const float* row = z + (size_t)gw * 1024;
  float a0 = 0.f, a1 = 0.f;
#pragma unroll
  for (int it = 0; it < 4; ++it) {
    int k = lane * 4 + it * 256;
    float4 v = *(const float4*)(row + k);
    float4 w01 = *(const float4*)(W2 + k * 2);
    float4 w23 = *(const float4*)(W2 + k * 2 + 4);
    a0 += v.x * w01.x + v.y * w01.z + v.z * w23.x + v.w * w23.z;
    a1 += v.x * w01.y + v.y * w01.w + v.z * w23.y + v.w * w23.w;
  }
#pragma unroll
  for (int off = 32; off; off >>= 1) {
    a0 += __shfl_down(a0, off);
    a1 += __shfl_down(a1, off);
  }
  if (lane == 0) {
    float l0 = a0 + b2[0], l1 = a1 + b2[1];
    float m = fmaxf(l0, l1);
    float lse = m + logf(expf(l0 - m) + expf(l1 - m));
    out[gw * 2 + 0] = l0 - lse;
    out[gw * 2 + 1] = l1 - lse;
  }
}

// ---------------------------------------------------------------------------
extern "C" void kernel_launch(void* const* d_in, const int* in_sizes, int n_in,
                              void* d_out, int out_size, void* d_ws, size_t ws_size,
                              hipStream_t stream) {
  (void)in_sizes; (void)n_in; (void)out_size; (void)ws_size;
  const float* fts    = (const float*)d_in[0];
  const int*   graph  = (const int*)d_in[1];
  const float* W_gat  = (const float*)d_in[3];
  const float* att_s  = (const float*)d_in[4];
  const float* att_d  = (const float*)d_in[5];
  const float* b_gat  = (const float*)d_in[6];
  const float* W1     = (const float*)d_in[7];
  const float* b1     = (const float*)d_in[8];
  const float* W2     = (const float*)d_in[9];
  const float* b2     = (const float*)d_in[10];
  float* out = (float*)d_out;

  char* ws = (char*)d_ws;
  size_t off = 0;
  auto alloc = [&](size_t bytes) -> void* {
    void* p = ws + off;
    off += (bytes + 255) & ~(size_t)255;
    return p;
  };
  const size_t TN = (size_t)T_STEPS * N_NODES;
  ushort_t* h_bf   = (ushort_t*)alloc(TN * HC * 2);     // 163.8 MB (fits L3)
  float*    yb_all = (float*)alloc(TN * CC * 4);        // 81.9 MB
  float*    z      = (float*)alloc(TN * CC * 4);        // 81.9 MB
  float*    as_    = (float*)alloc(TN * NH * 4);
  float*    ad_    = (float*)alloc(TN * NH * 4);
  int*      deg    = (int*)alloc((size_t)T_STEPS * N_NODES * 4);
  int*      rowptr = (int*)alloc((size_t)T_STEPS * (N_NODES + 1) * 4);
  int*      fill   = (int*)alloc((size_t)T_STEPS * N_NODES * 4);
  int*      ssrc   = (int*)alloc((size_t)T_STEPS * N_EDGES * 4);
  ushort_t* Bth    = (ushort_t*)alloc((size_t)HC * NFEAT * 2);
  ushort_t* Btl    = (ushort_t*)alloc((size_t)HC * NFEAT * 2);

  hipMemsetAsync(deg, 0, (size_t)T_STEPS * N_NODES * 4, stream);
  hipMemsetAsync(fill, 0, (size_t)T_STEPS * N_NODES * 4, stream);

  const int totE = T_STEPS * N_EDGES;
  count_kernel<<<(totE + 255) / 256, 256, 0, stream>>>(graph, deg);
  scan_kernel<<<T_STEPS, 1024, 0, stream>>>(deg, rowptr);
  scatter_kernel<<<(totE + 255) / 256, 256, 0, stream>>>(graph, rowptr, fill, ssrc);

  bsplit_kernel<<<(HC * NFEAT + 255) / 256, 256, 0, stream>>>(W_gat, Bth, Btl);

  // one fused GEMM over all T: [160000, 512] @ [512, 512] -> bf16 h
  gemm_mfma<<<dim3(HC / 128, (int)(TN / 128)), 256, 0, stream>>>(fts, Bth, Btl, h_bf);

  att_kernel<<<(int)(TN / 4), 256, 0, stream>>>(h_bf, att_s, att_d, as_, ad_);

  aggregate_kernel<<<dim3(N_NODES, T_STEPS), 256, 0, stream>>>(
      h_bf, as_, ad_, rowptr, ssrc, b_gat, yb_all);

  linear_kernel<<<2048, 256, 0, stream>>>(yb_all, W1, b1, z);

  final_kernel<<<(N_NODES * 64) / 256, 256, 0, stream>>>(z, W2, b2, out);
}